// Round 1
// baseline (4989.063 us; speedup 1.0000x reference)
//
#include <hip/hip_runtime.h>
#include <cmath>

// ---------------------------------------------------------------------------
// Hetero-SAGE GNN forward (4 layers, 10 relations, D=128) + edge classifier.
// fp32 everywhere (no fp32 MFMA on CDNA4 -> vector SGEMM).
// Pipeline per launch:
//   1. gather emb -> x_cur                          (6 kernels)
//   2. CSR build: hist -> scan -> scatter           (3 kernels, reused 4 layers)
//   3. per layer: memset x_next; per relation: mean-aggregate (CSR) then
//      fused K=256 GEMM  out[dst] += [mean|x_dst] @ [Wl;Wr] + bl  (+ReLU on
//      the last relation touching each dst type, layers 0..2)
//   4. fused classifier: gather rows, K=256 GEMM vs cls_w1, ReLU, dot w2,
//      pred -> d_out[1..], BCE loss mean -> d_out[0]
// ---------------------------------------------------------------------------

struct RelMeta {
  const int* ei[10];
  int E[10];
  int base[10];    // rowptr/counts base offset (ints)
  int esBase[10];  // edge_src base offset
  int nDst[10];
};

// ---------------- init gather: x[i] = emb[node_id[i]] ----------------------
__global__ __launch_bounds__(256) void gather_kernel(
    const float* __restrict__ emb, const int* __restrict__ nid,
    float* __restrict__ xout, int nRows) {
  int i = blockIdx.x * 256 + threadIdx.x;
  if (i >= nRows * 32) return;
  int row = i >> 5, q = i & 31;
  int s = nid[row];
  *(float4*)(xout + (size_t)row * 128 + q * 4) =
      *(const float4*)(emb + (size_t)s * 128 + q * 4);
}

// ---------------- CSR build ------------------------------------------------
__global__ __launch_bounds__(256) void hist_kernel(RelMeta m, int* __restrict__ counts) {
  int r = blockIdx.y;
  int e = blockIdx.x * 256 + threadIdx.x;
  if (e >= m.E[r]) return;
  int c = m.ei[r][m.E[r] + e];  // dst index (second row of ei)
  atomicAdd(&counts[m.base[r] + c], 1);
}

// one block per relation; exclusive scan of counts -> rowptr, counts becomes cursor
__global__ __launch_bounds__(1024) void scan_kernel(RelMeta m, int* __restrict__ counts,
                                                    int* __restrict__ rowptr) {
  int r = blockIdx.x;
  int n = m.nDst[r];
  int cb = m.base[r];
  int t = threadIdx.x;
  int seg = (n + 1023) >> 10;
  int begin = t * seg;
  int end = begin + seg; if (end > n) end = n;
  int s = 0;
  for (int i = begin; i < end; ++i) s += counts[cb + i];
  __shared__ int sums[1024];
  __shared__ int gsum[33];
  sums[t] = s;
  __syncthreads();
  if (t < 32) {
    int g = 0;
    #pragma unroll
    for (int i = 0; i < 32; ++i) g += sums[t * 32 + i];
    gsum[t + 1] = g;
  }
  __syncthreads();
  if (t == 0) {
    gsum[0] = 0;
    for (int i = 1; i <= 32; ++i) gsum[i] += gsum[i - 1];
  }
  __syncthreads();
  int g = t >> 5;
  int p = gsum[g];
  for (int i = g * 32; i < t; ++i) p += sums[i];
  int run = p;
  for (int i = begin; i < end; ++i) {
    int v = counts[cb + i];
    rowptr[cb + i] = run;
    counts[cb + i] = run;  // cursor for scatter
    run += v;
  }
  if (t == 0) rowptr[cb + n] = m.E[r];
}

__global__ __launch_bounds__(256) void scatter_kernel(RelMeta m, int* __restrict__ cursor,
                                                      int* __restrict__ esrc) {
  int r = blockIdx.y;
  int e = blockIdx.x * 256 + threadIdx.x;
  if (e >= m.E[r]) return;
  const int* ei = m.ei[r];
  int c = ei[m.E[r] + e];
  int pos = atomicAdd(&cursor[m.base[r] + c], 1);
  esrc[m.esBase[r] + pos] = ei[e];
}

// ---------------- mean aggregation over CSR --------------------------------
// 32 lanes per dst row (float4 each), 8 rows per 256-thread block
__global__ __launch_bounds__(256) void agg_kernel(
    const float* __restrict__ xsrc, const int* __restrict__ esrc,
    const int* __restrict__ rp, float* __restrict__ mean, int nDst) {
  int row = blockIdx.x * 8 + (threadIdx.x >> 5);
  if (row >= nDst) return;
  int t = threadIdx.x & 31;
  int e0 = rp[row], e1 = rp[row + 1];
  float4 acc = make_float4(0.f, 0.f, 0.f, 0.f);
  for (int e = e0; e < e1; ++e) {
    int s = esrc[e];
    float4 v = *(const float4*)(xsrc + (size_t)s * 128 + t * 4);
    acc.x += v.x; acc.y += v.y; acc.z += v.z; acc.w += v.w;
  }
  float inv = (e1 > e0) ? 1.f / (float)(e1 - e0) : 0.f;
  acc.x *= inv; acc.y *= inv; acc.z *= inv; acc.w *= inv;
  *(float4*)(mean + (size_t)row * 128 + t * 4) = acc;
}

// ---------------- relation GEMM: out += [A0|A1] @ [B0;B1] + bias -----------
// M x 256 x 128, BM=128, BK=16, 256 threads, 8x8 micro-tile
__global__ __launch_bounds__(256, 2) void gemm_rel(
    const float* __restrict__ A0, const float* __restrict__ A1,
    const float* __restrict__ B0, const float* __restrict__ B1,
    const float* __restrict__ bias, float* __restrict__ out,
    int M, int doRelu) {
  __shared__ float As[16][128];  // transposed: As[k][row]
  __shared__ float Bs[16][128];  // Bs[k][col]
  int tid = threadIdx.x;
  int tx = tid & 15, ty = tid >> 4;
  int blockRow = blockIdx.x * 128;
  float acc[8][8];
  #pragma unroll
  for (int i = 0; i < 8; ++i)
    #pragma unroll
    for (int j = 0; j < 8; ++j) acc[i][j] = 0.f;

  for (int kk = 0; kk < 16; ++kk) {
    const float* A = (kk < 8) ? A0 : A1;
    const float* B = (kk < 8) ? B0 : B1;
    int kb = (kk & 7) * 16;
    #pragma unroll
    for (int i = 0; i < 2; ++i) {
      int f = tid * 2 + i;
      int rr = f >> 2, qc = f & 3;
      int gr = blockRow + rr;
      float4 v = make_float4(0.f, 0.f, 0.f, 0.f);
      if (gr < M) v = *(const float4*)(A + (size_t)gr * 128 + kb + qc * 4);
      As[qc * 4 + 0][rr] = v.x; As[qc * 4 + 1][rr] = v.y;
      As[qc * 4 + 2][rr] = v.z; As[qc * 4 + 3][rr] = v.w;
      int kr = f >> 5, c4 = f & 31;
      *(float4*)&Bs[kr][c4 * 4] =
          *(const float4*)(B + (size_t)(kb + kr) * 128 + c4 * 4);
    }
    __syncthreads();
    #pragma unroll
    for (int k = 0; k < 16; ++k) {
      float a[8], b[8];
      *(float4*)&a[0] = *(float4*)&As[k][ty * 8];
      *(float4*)&a[4] = *(float4*)&As[k][ty * 8 + 4];
      *(float4*)&b[0] = *(float4*)&Bs[k][tx * 8];
      *(float4*)&b[4] = *(float4*)&Bs[k][tx * 8 + 4];
      #pragma unroll
      for (int i = 0; i < 8; ++i)
        #pragma unroll
        for (int j = 0; j < 8; ++j) acc[i][j] += a[i] * b[j];
    }
    __syncthreads();
  }

  float bv[8];
  *(float4*)&bv[0] = *(const float4*)(bias + tx * 8);
  *(float4*)&bv[4] = *(const float4*)(bias + tx * 8 + 4);
  #pragma unroll
  for (int i = 0; i < 8; ++i) {
    int gr = blockRow + ty * 8 + i;
    if (gr >= M) continue;
    float* o = out + (size_t)gr * 128 + tx * 8;
    float4 o0 = *(float4*)o;
    float4 o1 = *(float4*)(o + 4);
    float v[8];
    v[0] = o0.x + acc[i][0] + bv[0]; v[1] = o0.y + acc[i][1] + bv[1];
    v[2] = o0.z + acc[i][2] + bv[2]; v[3] = o0.w + acc[i][3] + bv[3];
    v[4] = o1.x + acc[i][4] + bv[4]; v[5] = o1.y + acc[i][5] + bv[5];
    v[6] = o1.z + acc[i][6] + bv[6]; v[7] = o1.w + acc[i][7] + bv[7];
    if (doRelu) {
      #pragma unroll
      for (int j = 0; j < 8; ++j) v[j] = fmaxf(v[j], 0.f);
    }
    *(float4*)o = make_float4(v[0], v[1], v[2], v[3]);
    *(float4*)(o + 4) = make_float4(v[4], v[5], v[6], v[7]);
  }
}

// ---------------- fused classifier -----------------------------------------
// rows gathered via edge_label_index; h = relu([zv|zd]@W1 + b1) kept in regs;
// pred = h.w2 + b2 via 16-lane shuffle reduce; BCE loss atomically accumulated
__global__ __launch_bounds__(256, 2) void gemm_cls(
    const float* __restrict__ xv, const float* __restrict__ xd,
    const int* __restrict__ eli, const float* __restrict__ W1,
    const float* __restrict__ b1, const float* __restrict__ w2,
    const float* __restrict__ b2, const float* __restrict__ y,
    float* __restrict__ lossOut, float* __restrict__ pred, int M) {
  __shared__ float As[16][128];
  __shared__ float Bs[16][128];
  __shared__ int idxA[128];
  __shared__ int idxB[128];
  int tid = threadIdx.x;
  int tx = tid & 15, ty = tid >> 4;
  int blockRow = blockIdx.x * 128;
  if (tid < 128) {
    int gr = blockRow + tid;
    idxA[tid] = (gr < M) ? eli[gr] : 0;
  } else {
    int t2 = tid - 128;
    int gr = blockRow + t2;
    idxB[t2] = (gr < M) ? eli[M + gr] : 0;
  }
  float acc[8][8];
  #pragma unroll
  for (int i = 0; i < 8; ++i)
    #pragma unroll
    for (int j = 0; j < 8; ++j) acc[i][j] = 0.f;
  __syncthreads();

  for (int kk = 0; kk < 16; ++kk) {
    int kb = (kk & 7) * 16;
    #pragma unroll
    for (int i = 0; i < 2; ++i) {
      int f = tid * 2 + i;
      int rr = f >> 2, qc = f & 3;
      const float* src = (kk < 8) ? (xv + (size_t)idxA[rr] * 128)
                                  : (xd + (size_t)idxB[rr] * 128);
      float4 v = *(const float4*)(src + kb + qc * 4);
      As[qc * 4 + 0][rr] = v.x; As[qc * 4 + 1][rr] = v.y;
      As[qc * 4 + 2][rr] = v.z; As[qc * 4 + 3][rr] = v.w;
      int kr = f >> 5, c4 = f & 31;
      *(float4*)&Bs[kr][c4 * 4] =
          *(const float4*)(W1 + (size_t)(kk * 16 + kr) * 128 + c4 * 4);
    }
    __syncthreads();
    #pragma unroll
    for (int k = 0; k < 16; ++k) {
      float a[8], b[8];
      *(float4*)&a[0] = *(float4*)&As[k][ty * 8];
      *(float4*)&a[4] = *(float4*)&As[k][ty * 8 + 4];
      *(float4*)&b[0] = *(float4*)&Bs[k][tx * 8];
      *(float4*)&b[4] = *(float4*)&Bs[k][tx * 8 + 4];
      #pragma unroll
      for (int i = 0; i < 8; ++i)
        #pragma unroll
        for (int j = 0; j < 8; ++j) acc[i][j] += a[i] * b[j];
    }
    __syncthreads();
  }

  float b1v[8], w2v[8];
  *(float4*)&b1v[0] = *(const float4*)(b1 + tx * 8);
  *(float4*)&b1v[4] = *(const float4*)(b1 + tx * 8 + 4);
  *(float4*)&w2v[0] = *(const float4*)(w2 + tx * 8);
  *(float4*)&w2v[4] = *(const float4*)(w2 + tx * 8 + 4);
  float b2v = b2[0];
  float local = 0.f;
  #pragma unroll
  for (int i = 0; i < 8; ++i) {
    float p = 0.f;
    #pragma unroll
    for (int j = 0; j < 8; ++j) {
      float h = fmaxf(acc[i][j] + b1v[j], 0.f);
      p += h * w2v[j];
    }
    p += __shfl_xor(p, 1);
    p += __shfl_xor(p, 2);
    p += __shfl_xor(p, 4);
    p += __shfl_xor(p, 8);
    int gr = blockRow + ty * 8 + i;
    if (tx == 0 && gr < M) {
      float z = p + b2v;
      pred[gr] = z;
      // stable softplus(z) - z*y
      float lv = fmaxf(z, 0.f) + log1pf(expf(-fabsf(z))) - z * y[gr];
      local += lv;
    }
  }
  __shared__ float red[16];
  if (tx == 0) red[ty] = local;
  __syncthreads();
  if (tid == 0) {
    float s = 0.f;
    #pragma unroll
    for (int i = 0; i < 16; ++i) s += red[i];
    atomicAdd(lossOut, s * (1.0f / 200000.0f));
  }
}

// ---------------------------------------------------------------------------
extern "C" void kernel_launch(void* const* d_in, const int* in_sizes, int n_in,
                              void* d_out, int out_size, void* d_ws, size_t ws_size,
                              hipStream_t stream) {
  static const int kRows[6] = {20000, 100000, 4000, 8000, 10000, 4000};
  static const int kOff[6]  = {0, 20000, 120000, 124000, 132000, 142000};
  static const int kSrcT[10] = {0, 1, 1, 2, 1, 3, 1, 4, 1, 5};
  static const int kDstT[10] = {1, 0, 2, 1, 3, 1, 4, 1, 5, 1};
  static const int kE[10] = {100000, 100000, 300000, 300000, 200000,
                             200000, 250000, 250000, 300000, 300000};
  static const int kRpBase[10] = {0, 100001, 120002, 124003, 224004,
                                  232005, 332006, 342007, 442008, 446009};
  static const int kEsBase[10] = {0, 100000, 200000, 500000, 800000,
                                  1000000, 1200000, 1450000, 1700000, 2000000};
  // last relation writing each dst type -> apply ReLU there (layers 0..2)
  static const int kRelu[10] = {0, 1, 1, 0, 1, 0, 1, 0, 1, 1};

  const int* nid[6]; const float* emb[6];
  for (int t = 0; t < 6; ++t) {
    nid[t] = (const int*)d_in[2 * t];
    emb[t] = (const float*)d_in[2 * t + 1];
  }
  const float* W_l = (const float*)d_in[22];
  const float* b_l = (const float*)d_in[23];
  const float* W_r = (const float*)d_in[24];
  const float* cw1 = (const float*)d_in[25];
  const float* cb1 = (const float*)d_in[26];
  const float* cw2 = (const float*)d_in[27];
  const float* cb2 = (const float*)d_in[28];
  const int* eli = (const int*)d_in[29];
  const float* ylab = (const float*)d_in[30];

  const size_t XFLOATS = 146000UL * 128UL;        // 18,688,000 floats
  float* xA = (float*)d_ws;
  float* xB = xA + XFLOATS;
  float* meanBuf = xB + XFLOATS;                  // 100000*128 floats max
  int* rowptr = (int*)(meanBuf + 100000UL * 128UL);
  int* counts = rowptr + 546010;
  int* esrc = counts + 546010;                    // 2,300,000 ints

  RelMeta m;
  for (int r = 0; r < 10; ++r) {
    m.ei[r] = (const int*)d_in[12 + r];
    m.E[r] = kE[r];
    m.base[r] = kRpBase[r];
    m.esBase[r] = kEsBase[r];
    m.nDst[r] = kRows[kDstT[r]];
  }

  // init: zero counters, gather embeddings into x_cur
  hipMemsetAsync(counts, 0, 546010 * sizeof(int), stream);
  for (int t = 0; t < 6; ++t) {
    int nf4 = kRows[t] * 32;
    gather_kernel<<<(nf4 + 255) / 256, 256, 0, stream>>>(
        emb[t], nid[t], xA + (size_t)kOff[t] * 128, kRows[t]);
  }
  // CSR build (shared across all 4 layers)
  dim3 egrid((300000 + 255) / 256, 10);
  hist_kernel<<<egrid, 256, 0, stream>>>(m, counts);
  scan_kernel<<<10, 1024, 0, stream>>>(m, counts, rowptr);
  scatter_kernel<<<egrid, 256, 0, stream>>>(m, counts, esrc);

  float* xc = xA;
  float* xn = xB;
  for (int l = 0; l < 4; ++l) {
    hipMemsetAsync(xn, 0, XFLOATS * sizeof(float), stream);
    for (int r = 0; r < 10; ++r) {
      int nDst = kRows[kDstT[r]];
      agg_kernel<<<(nDst + 7) / 8, 256, 0, stream>>>(
          xc + (size_t)kOff[kSrcT[r]] * 128, esrc + kEsBase[r],
          rowptr + kRpBase[r], meanBuf, nDst);
      int doRelu = (l < 3) && kRelu[r];
      gemm_rel<<<(nDst + 127) / 128, 256, 0, stream>>>(
          meanBuf, xc + (size_t)kOff[kDstT[r]] * 128,
          W_l + (size_t)(l * 10 + r) * 16384,
          W_r + (size_t)(l * 10 + r) * 16384,
          b_l + (size_t)(l * 10 + r) * 128,
          xn + (size_t)kOff[kDstT[r]] * 128, nDst, doRelu);
    }
    float* tmp = xc; xc = xn; xn = tmp;
  }

  // classifier (fused): pred -> d_out[1..], loss -> d_out[0]
  hipMemsetAsync(d_out, 0, sizeof(float), stream);
  const int ML = 200000;
  gemm_cls<<<(ML + 127) / 128, 256, 0, stream>>>(
      xc + (size_t)kOff[1] * 128, xc + (size_t)kOff[5] * 128, eli,
      cw1, cb1, cw2, cb2, ylab, (float*)d_out, (float*)d_out + 1, ML);
}

// Round 2
// 3162.061 us; speedup vs baseline: 1.5778x; 1.5778x over previous
//
#include <hip/hip_runtime.h>
#include <cmath>

// ---------------------------------------------------------------------------
// Hetero-SAGE GNN (4 layers, 10 relations, D=128) + edge classifier. fp32.
// R1 restructure:
//  - per-dst-type fused GEMM: visit = [5 means | x_v] @ [Wl..;SumWr] (K=768),
//    means computed on-the-fly in A-tile staging (no mean buffer, no RMW,
//    no x_next memset). Small types: standalone agg + merged K=256 GEMM.
//  - 3-phase global scan over gap-free counts; global prefix == esrc position.
//  - prep kernel stacks B/bias per (layer, dst type).
// ---------------------------------------------------------------------------

#define NREL 10
static const int kCbc[NREL]   = {0, 100000, 120000, 124000, 224000,
                                 232000, 332000, 342000, 442000, 446000};
static const int kEh[NREL]    = {100000, 100000, 300000, 300000, 200000,
                                 200000, 250000, 250000, 300000, 300000};
#define NCOUNTS 546000
#define NEDGES  2300000
#define NVISIT  100000
#define PER_LAYER_B 262912   // 768*128 + 5*256*128 + 6*128 floats

struct RelMeta { const int* ei[NREL]; int E[NREL]; int cbc[NREL]; };
struct GatherMeta { const float* emb[6]; const int* nid[6]; int rows[6]; int off[6]; };
struct AggMeta { const int* rp[5]; float* mean[5]; int M[5]; };
struct SmallMeta { const float* mean[5]; const float* xdst[5];
                   const float* B[5]; const float* bias[5];
                   float* out[5]; int M[5]; };
struct VisitMeta { const float* xs[5]; const int* rp[5]; };

// ---------------- init gather: x[off+i] = emb[nid[i]] ----------------------
__global__ __launch_bounds__(256) void gather_all(GatherMeta g, float* __restrict__ x) {
  int t = blockIdx.y;
  int i = blockIdx.x * 256 + threadIdx.x;
  if (i >= g.rows[t] * 32) return;
  int row = i >> 5, q = i & 31;
  int s = g.nid[t][row];
  *(float4*)(x + (size_t)(g.off[t] + row) * 128 + q * 4) =
      *(const float4*)(g.emb[t] + (size_t)s * 128 + q * 4);
}

// ---------------- CSR build ------------------------------------------------
__global__ __launch_bounds__(256) void hist_kernel(RelMeta m, int* __restrict__ counts) {
  int r = blockIdx.y;
  int e = blockIdx.x * 256 + threadIdx.x;
  if (e >= m.E[r]) return;
  int c = m.ei[r][m.E[r] + e];
  atomicAdd(&counts[m.cbc[r] + c], 1);
}

__global__ __launch_bounds__(1024) void scan1(const int* __restrict__ counts,
                                              int* __restrict__ partials) {
  __shared__ int s[1024];
  int i = blockIdx.x * 1024 + threadIdx.x;
  s[threadIdx.x] = (i < NCOUNTS) ? counts[i] : 0;
  __syncthreads();
  for (int off = 512; off > 0; off >>= 1) {
    if (threadIdx.x < off) s[threadIdx.x] += s[threadIdx.x + off];
    __syncthreads();
  }
  if (threadIdx.x == 0) partials[blockIdx.x] = s[0];
}

__global__ __launch_bounds__(1024) void scan2(int* __restrict__ partials, int nb) {
  __shared__ int s[1024];
  int t = threadIdx.x;
  int v = (t < nb) ? partials[t] : 0;
  s[t] = v;
  __syncthreads();
  for (int off = 1; off < 1024; off <<= 1) {
    int add = (t >= off) ? s[t - off] : 0;
    __syncthreads();
    s[t] += add;
    __syncthreads();
  }
  if (t < nb) partials[t] = s[t] - v;  // exclusive
}

__global__ __launch_bounds__(1024) void scan3(int* __restrict__ counts,
                                              int* __restrict__ prefix,
                                              const int* __restrict__ partials) {
  __shared__ int s[1024];
  int t = threadIdx.x;
  int i = blockIdx.x * 1024 + t;
  int v = (i < NCOUNTS) ? counts[i] : 0;
  s[t] = v;
  __syncthreads();
  for (int off = 1; off < 1024; off <<= 1) {
    int add = (t >= off) ? s[t - off] : 0;
    __syncthreads();
    s[t] += add;
    __syncthreads();
  }
  int P = partials[blockIdx.x] + s[t] - v;  // global exclusive prefix
  if (i < NCOUNTS) { prefix[i] = P; counts[i] = P; /* cursor */ }
  if (blockIdx.x == 0 && t == 0) prefix[NCOUNTS] = NEDGES;
}

__global__ __launch_bounds__(256) void scatter_kernel(RelMeta m, int* __restrict__ cursor,
                                                      int* __restrict__ esrc) {
  int r = blockIdx.y;
  int e = blockIdx.x * 256 + threadIdx.x;
  if (e >= m.E[r]) return;
  const int* ei = m.ei[r];
  int c = ei[m.E[r] + e];
  int pos = atomicAdd(&cursor[m.cbc[r] + c], 1);
  esrc[pos] = ei[e];
}

// ---------------- stacked B / bias prep ------------------------------------
// per layer: [0,98304): visit B rows 0..639 = Wl{pv,sv,prv,dv,drv}, 640..767 = SumWr
//            [98304,262144): small t: [Wl_r; Wr_r] 256x128
//            [262144,262272): visit bias = sum b; [262272,+5*128): small biases
__global__ __launch_bounds__(256) void prep_B(const float* __restrict__ W_l,
                                              const float* __restrict__ b_l,
                                              const float* __restrict__ W_r,
                                              float* __restrict__ Bcat) {
  const int visitRel[5] = {0, 3, 5, 7, 9};
  const int inRel[5] = {1, 2, 4, 6, 8};
  int gid = blockIdx.x * 256 + threadIdx.x;
  if (gid >= 4 * PER_LAYER_B) return;
  int l = gid / PER_LAYER_B, o = gid % PER_LAYER_B;
  float val;
  if (o < 98304) {
    int row = o >> 7, c = o & 127;
    if (row < 640) {
      int r = visitRel[row >> 7];
      val = W_l[(size_t)(l * 10 + r) * 16384 + (row & 127) * 128 + c];
    } else {
      int kr = row - 640;
      val = 0.f;
      #pragma unroll
      for (int q = 0; q < 5; ++q)
        val += W_r[(size_t)(l * 10 + visitRel[q]) * 16384 + kr * 128 + c];
    }
  } else if (o < 262144) {
    int o2 = o - 98304;
    int t = o2 >> 15, o3 = o2 & 32767;
    int row = o3 >> 7, c = o3 & 127;
    int r = inRel[t];
    val = (row < 128) ? W_l[(size_t)(l * 10 + r) * 16384 + row * 128 + c]
                      : W_r[(size_t)(l * 10 + r) * 16384 + (row - 128) * 128 + c];
  } else if (o < 262272) {
    int c = o - 262144;
    val = 0.f;
    #pragma unroll
    for (int q = 0; q < 5; ++q) val += b_l[(l * 10 + visitRel[q]) * 128 + c];
  } else {
    int t = (o - 262272) >> 7, c = (o - 262272) & 127;
    val = b_l[(l * 10 + inRel[t]) * 128 + c];
  }
  Bcat[(size_t)l * PER_LAYER_B + o] = val;
}

// ---------------- mean aggregation for small dst types ---------------------
__global__ __launch_bounds__(256) void agg_all(AggMeta m, const float* __restrict__ xv,
                                               const int* __restrict__ esrc) {
  int t = blockIdx.y;
  int row = blockIdx.x * 8 + (threadIdx.x >> 5);
  if (row >= m.M[t]) return;
  int q = threadIdx.x & 31;
  const int* rp = m.rp[t];
  int e0 = rp[row], e1 = rp[row + 1];
  float4 acc = make_float4(0.f, 0.f, 0.f, 0.f);
  for (int e = e0; e < e1; ++e) {
    int s = esrc[e];
    float4 v = *(const float4*)(xv + (size_t)s * 128 + q * 4);
    acc.x += v.x; acc.y += v.y; acc.z += v.z; acc.w += v.w;
  }
  float inv = (e1 > e0) ? 1.f / (float)(e1 - e0) : 0.f;
  acc.x *= inv; acc.y *= inv; acc.z *= inv; acc.w *= inv;
  *(float4*)(m.mean[t] + (size_t)row * 128 + q * 4) = acc;
}

// ---------------- visit fused gather-GEMM: M x 768 x 128 -------------------
__global__ __launch_bounds__(256, 2) void gemm_visit(
    VisitMeta vm, const float* __restrict__ xVisit, const int* __restrict__ esrc,
    const float* __restrict__ B, const float* __restrict__ bias,
    float* __restrict__ out, int M, int doRelu) {
  __shared__ float As[16][128];
  __shared__ float Bs[16][128];
  __shared__ int rps[5][129];
  __shared__ float invd[5][128];
  int tid = threadIdx.x;
  int tx = tid & 15, ty = tid >> 4;
  int blockRow = blockIdx.x * 128;
  for (int idx = tid; idx < 5 * 129; idx += 256) {
    int r = idx / 129, i = idx % 129;
    int gr = blockRow + i; if (gr > M) gr = M;
    rps[r][i] = vm.rp[r][gr];
  }
  __syncthreads();
  for (int idx = tid; idx < 5 * 128; idx += 256) {
    int r = idx >> 7, i = idx & 127;
    int d = rps[r][i + 1] - rps[r][i];
    invd[r][i] = (d > 0) ? 1.f / (float)d : 0.f;
  }
  float acc[8][8];
  #pragma unroll
  for (int i = 0; i < 8; ++i)
    #pragma unroll
    for (int j = 0; j < 8; ++j) acc[i][j] = 0.f;
  __syncthreads();

  int rr = tid >> 1;           // tile row handled by this thread
  int half = tid & 1;          // which 8 floats of the 16-wide k-block
  for (int kk = 0; kk < 48; ++kk) {
    int seg = kk >> 3, kb = (kk & 7) * 16;
    float4 v0 = make_float4(0.f, 0.f, 0.f, 0.f);
    float4 v1 = make_float4(0.f, 0.f, 0.f, 0.f);
    if (seg < 5) {
      int e0 = rps[seg][rr], e1 = rps[seg][rr + 1];
      const float* xs = vm.xs[seg];
      for (int e = e0; e < e1; ++e) {
        int s = esrc[e];
        const float* p = xs + (size_t)s * 128 + kb + half * 8;
        float4 w0 = *(const float4*)p;
        float4 w1 = *(const float4*)(p + 4);
        v0.x += w0.x; v0.y += w0.y; v0.z += w0.z; v0.w += w0.w;
        v1.x += w1.x; v1.y += w1.y; v1.z += w1.z; v1.w += w1.w;
      }
      float iv = invd[seg][rr];
      v0.x *= iv; v0.y *= iv; v0.z *= iv; v0.w *= iv;
      v1.x *= iv; v1.y *= iv; v1.z *= iv; v1.w *= iv;
    } else {
      int gr = blockRow + rr;
      if (gr < M) {
        const float* p = xVisit + (size_t)gr * 128 + kb + half * 8;
        v0 = *(const float4*)p;
        v1 = *(const float4*)(p + 4);
      }
    }
    int c0 = half * 8;
    As[c0 + 0][rr] = v0.x; As[c0 + 1][rr] = v0.y;
    As[c0 + 2][rr] = v0.z; As[c0 + 3][rr] = v0.w;
    As[c0 + 4][rr] = v1.x; As[c0 + 5][rr] = v1.y;
    As[c0 + 6][rr] = v1.z; As[c0 + 7][rr] = v1.w;
    #pragma unroll
    for (int i = 0; i < 2; ++i) {
      int f = tid * 2 + i;
      int kr = f >> 5, c4 = f & 31;
      *(float4*)&Bs[kr][c4 * 4] =
          *(const float4*)(B + (size_t)(kk * 16 + kr) * 128 + c4 * 4);
    }
    __syncthreads();
    #pragma unroll
    for (int k = 0; k < 16; ++k) {
      float a[8], b[8];
      *(float4*)&a[0] = *(float4*)&As[k][ty * 8];
      *(float4*)&a[4] = *(float4*)&As[k][ty * 8 + 4];
      *(float4*)&b[0] = *(float4*)&Bs[k][tx * 8];
      *(float4*)&b[4] = *(float4*)&Bs[k][tx * 8 + 4];
      #pragma unroll
      for (int i = 0; i < 8; ++i)
        #pragma unroll
        for (int j = 0; j < 8; ++j) acc[i][j] += a[i] * b[j];
    }
    __syncthreads();
  }

  float bv[8];
  *(float4*)&bv[0] = *(const float4*)(bias + tx * 8);
  *(float4*)&bv[4] = *(const float4*)(bias + tx * 8 + 4);
  #pragma unroll
  for (int i = 0; i < 8; ++i) {
    int gr = blockRow + ty * 8 + i;
    if (gr >= M) continue;
    float v[8];
    #pragma unroll
    for (int j = 0; j < 8; ++j) {
      v[j] = acc[i][j] + bv[j];
      if (doRelu) v[j] = fmaxf(v[j], 0.f);
    }
    float* o = out + (size_t)gr * 128 + tx * 8;
    *(float4*)o = make_float4(v[0], v[1], v[2], v[3]);
    *(float4*)(o + 4) = make_float4(v[4], v[5], v[6], v[7]);
  }
}

// ---------------- small-type GEMM (merged, write-only): M x 256 x 128 ------
__global__ __launch_bounds__(256, 2) void gemm_small(SmallMeta sm, int doRelu) {
  int t = blockIdx.y;
  int M = sm.M[t];
  int blockRow = blockIdx.x * 128;
  if (blockRow >= M) return;
  __shared__ float As[16][128];
  __shared__ float Bs[16][128];
  int tid = threadIdx.x;
  int tx = tid & 15, ty = tid >> 4;
  const float* B = sm.B[t];
  float acc[8][8];
  #pragma unroll
  for (int i = 0; i < 8; ++i)
    #pragma unroll
    for (int j = 0; j < 8; ++j) acc[i][j] = 0.f;

  for (int kk = 0; kk < 16; ++kk) {
    const float* A = (kk < 8) ? sm.mean[t] : sm.xdst[t];
    int kb = (kk & 7) * 16;
    #pragma unroll
    for (int i = 0; i < 2; ++i) {
      int f = tid * 2 + i;
      int rr = f >> 2, qc = f & 3;
      int gr = blockRow + rr;
      float4 v = make_float4(0.f, 0.f, 0.f, 0.f);
      if (gr < M) v = *(const float4*)(A + (size_t)gr * 128 + kb + qc * 4);
      As[qc * 4 + 0][rr] = v.x; As[qc * 4 + 1][rr] = v.y;
      As[qc * 4 + 2][rr] = v.z; As[qc * 4 + 3][rr] = v.w;
      int kr = f >> 5, c4 = f & 31;
      *(float4*)&Bs[kr][c4 * 4] =
          *(const float4*)(B + (size_t)(kk * 16 + kr) * 128 + c4 * 4);
    }
    __syncthreads();
    #pragma unroll
    for (int k = 0; k < 16; ++k) {
      float a[8], b[8];
      *(float4*)&a[0] = *(float4*)&As[k][ty * 8];
      *(float4*)&a[4] = *(float4*)&As[k][ty * 8 + 4];
      *(float4*)&b[0] = *(float4*)&Bs[k][tx * 8];
      *(float4*)&b[4] = *(float4*)&Bs[k][tx * 8 + 4];
      #pragma unroll
      for (int i = 0; i < 8; ++i)
        #pragma unroll
        for (int j = 0; j < 8; ++j) acc[i][j] += a[i] * b[j];
    }
    __syncthreads();
  }

  float bv[8];
  *(float4*)&bv[0] = *(const float4*)(sm.bias[t] + tx * 8);
  *(float4*)&bv[4] = *(const float4*)(sm.bias[t] + tx * 8 + 4);
  #pragma unroll
  for (int i = 0; i < 8; ++i) {
    int gr = blockRow + ty * 8 + i;
    if (gr >= M) continue;
    float v[8];
    #pragma unroll
    for (int j = 0; j < 8; ++j) {
      v[j] = acc[i][j] + bv[j];
      if (doRelu) v[j] = fmaxf(v[j], 0.f);
    }
    float* o = sm.out[t] + (size_t)gr * 128 + tx * 8;
    *(float4*)o = make_float4(v[0], v[1], v[2], v[3]);
    *(float4*)(o + 4) = make_float4(v[4], v[5], v[6], v[7]);
  }
}

// ---------------- fused classifier -----------------------------------------
__global__ __launch_bounds__(256, 2) void gemm_cls(
    const float* __restrict__ xv, const float* __restrict__ xd,
    const int* __restrict__ eli, const float* __restrict__ W1,
    const float* __restrict__ b1, const float* __restrict__ w2,
    const float* __restrict__ b2, const float* __restrict__ y,
    float* __restrict__ lossOut, float* __restrict__ pred, int M) {
  __shared__ float As[16][128];
  __shared__ float Bs[16][128];
  __shared__ int idxA[128];
  __shared__ int idxB[128];
  int tid = threadIdx.x;
  int tx = tid & 15, ty = tid >> 4;
  int blockRow = blockIdx.x * 128;
  if (tid < 128) {
    int gr = blockRow + tid;
    idxA[tid] = (gr < M) ? eli[gr] : 0;
  } else {
    int t2 = tid - 128;
    int gr = blockRow + t2;
    idxB[t2] = (gr < M) ? eli[M + gr] : 0;
  }
  float acc[8][8];
  #pragma unroll
  for (int i = 0; i < 8; ++i)
    #pragma unroll
    for (int j = 0; j < 8; ++j) acc[i][j] = 0.f;
  __syncthreads();

  for (int kk = 0; kk < 16; ++kk) {
    int kb = (kk & 7) * 16;
    #pragma unroll
    for (int i = 0; i < 2; ++i) {
      int f = tid * 2 + i;
      int rr = f >> 2, qc = f & 3;
      const float* src = (kk < 8) ? (xv + (size_t)idxA[rr] * 128)
                                  : (xd + (size_t)idxB[rr] * 128);
      float4 v = *(const float4*)(src + kb + qc * 4);
      As[qc * 4 + 0][rr] = v.x; As[qc * 4 + 1][rr] = v.y;
      As[qc * 4 + 2][rr] = v.z; As[qc * 4 + 3][rr] = v.w;
      int kr = f >> 5, c4 = f & 31;
      *(float4*)&Bs[kr][c4 * 4] =
          *(const float4*)(W1 + (size_t)(kk * 16 + kr) * 128 + c4 * 4);
    }
    __syncthreads();
    #pragma unroll
    for (int k = 0; k < 16; ++k) {
      float a[8], b[8];
      *(float4*)&a[0] = *(float4*)&As[k][ty * 8];
      *(float4*)&a[4] = *(float4*)&As[k][ty * 8 + 4];
      *(float4*)&b[0] = *(float4*)&Bs[k][tx * 8];
      *(float4*)&b[4] = *(float4*)&Bs[k][tx * 8 + 4];
      #pragma unroll
      for (int i = 0; i < 8; ++i)
        #pragma unroll
        for (int j = 0; j < 8; ++j) acc[i][j] += a[i] * b[j];
    }
    __syncthreads();
  }

  float b1v[8], w2v[8];
  *(float4*)&b1v[0] = *(const float4*)(b1 + tx * 8);
  *(float4*)&b1v[4] = *(const float4*)(b1 + tx * 8 + 4);
  *(float4*)&w2v[0] = *(const float4*)(w2 + tx * 8);
  *(float4*)&w2v[4] = *(const float4*)(w2 + tx * 8 + 4);
  float b2v = b2[0];
  float local = 0.f;
  #pragma unroll
  for (int i = 0; i < 8; ++i) {
    float p = 0.f;
    #pragma unroll
    for (int j = 0; j < 8; ++j) {
      float h = fmaxf(acc[i][j] + b1v[j], 0.f);
      p += h * w2v[j];
    }
    p += __shfl_xor(p, 1);
    p += __shfl_xor(p, 2);
    p += __shfl_xor(p, 4);
    p += __shfl_xor(p, 8);
    int gr = blockRow + ty * 8 + i;
    if (tx == 0 && gr < M) {
      float z = p + b2v;
      pred[gr] = z;
      float lv = fmaxf(z, 0.f) + log1pf(expf(-fabsf(z))) - z * y[gr];
      local += lv;
    }
  }
  __shared__ float red[16];
  if (tx == 0) red[ty] = local;
  __syncthreads();
  if (tid == 0) {
    float s = 0.f;
    #pragma unroll
    for (int i = 0; i < 16; ++i) s += red[i];
    atomicAdd(lossOut, s * (1.0f / 200000.0f));
  }
}

// ---------------------------------------------------------------------------
extern "C" void kernel_launch(void* const* d_in, const int* in_sizes, int n_in,
                              void* d_out, int out_size, void* d_ws, size_t ws_size,
                              hipStream_t stream) {
  static const int kRows[6] = {20000, 100000, 4000, 8000, 10000, 4000};
  static const int kOff[6]  = {0, 20000, 120000, 124000, 132000, 142000};
  // small dst types (order: patient, symptom, procedure, disease, drug)
  static const int kSmallT[5]   = {0, 2, 3, 4, 5};
  static const int kCbcIn[5]    = {100000, 120000, 224000, 332000, 442000}; // rel vp,vs,vpr,vd,vdr
  static const int kCbcVisit[5] = {0, 124000, 232000, 342000, 446000};      // rel pv,sv,prv,dv,drv
  static const int kMeanOff[5]  = {0, 20000, 24000, 32000, 42000};

  const float* W_l = (const float*)d_in[22];
  const float* b_l = (const float*)d_in[23];
  const float* W_r = (const float*)d_in[24];
  const float* cw1 = (const float*)d_in[25];
  const float* cb1 = (const float*)d_in[26];
  const float* cw2 = (const float*)d_in[27];
  const float* cb2 = (const float*)d_in[28];
  const int* eli = (const int*)d_in[29];
  const float* ylab = (const float*)d_in[30];

  // workspace layout (floats/ints)
  const size_t XFLOATS = 146000UL * 128UL;  // 18,688,000
  float* xA = (float*)d_ws;
  float* xB = xA + XFLOATS;
  float* meanS = xB + XFLOATS;                       // 46000*128 floats
  int* prefix = (int*)(meanS + 46000UL * 128UL);     // 546,004 ints (padded)
  int* counts = prefix + 546004;                     // 546,000 ints (doubles as cursor)
  int* esrc = counts + NCOUNTS;                      // 2,300,000 ints
  int* partials = esrc + NEDGES;                     // 1,024 ints
  float* Bcat = (float*)(partials + 1024);           // 4 * PER_LAYER_B floats

  RelMeta rm;
  for (int r = 0; r < NREL; ++r) {
    rm.ei[r] = (const int*)d_in[12 + r];
    rm.E[r] = kEh[r];
    rm.cbc[r] = kCbc[r];
  }

  hipMemsetAsync(counts, 0, NCOUNTS * sizeof(int), stream);
  hipMemsetAsync(d_out, 0, sizeof(float), stream);

  prep_B<<<(4 * PER_LAYER_B + 255) / 256, 256, 0, stream>>>(W_l, b_l, W_r, Bcat);

  GatherMeta gm;
  for (int t = 0; t < 6; ++t) {
    gm.nid[t] = (const int*)d_in[2 * t];
    gm.emb[t] = (const float*)d_in[2 * t + 1];
    gm.rows[t] = kRows[t];
    gm.off[t] = kOff[t];
  }
  gather_all<<<dim3(12500, 6), 256, 0, stream>>>(gm, xA);

  dim3 egrid(1172, NREL);
  hist_kernel<<<egrid, 256, 0, stream>>>(rm, counts);
  scan1<<<534, 1024, 0, stream>>>(counts, partials);
  scan2<<<1, 1024, 0, stream>>>(partials, 534);
  scan3<<<534, 1024, 0, stream>>>(counts, prefix, partials);
  scatter_kernel<<<egrid, 256, 0, stream>>>(rm, counts, esrc);

  float* xc = xA;
  float* xn = xB;
  for (int l = 0; l < 4; ++l) {
    int doRelu = (l < 3);
    float* LB = Bcat + (size_t)l * PER_LAYER_B;

    AggMeta am;
    for (int t = 0; t < 5; ++t) {
      am.rp[t] = prefix + kCbcIn[t];
      am.mean[t] = meanS + (size_t)kMeanOff[t] * 128;
      am.M[t] = kRows[kSmallT[t]];
    }
    agg_all<<<dim3(2500, 5), 256, 0, stream>>>(am, xc + (size_t)kOff[1] * 128, esrc);

    SmallMeta sm;
    for (int t = 0; t < 5; ++t) {
      sm.mean[t] = meanS + (size_t)kMeanOff[t] * 128;
      sm.xdst[t] = xc + (size_t)kOff[kSmallT[t]] * 128;
      sm.B[t] = LB + 98304 + (size_t)t * 32768;
      sm.bias[t] = LB + 262272 + t * 128;
      sm.out[t] = xn + (size_t)kOff[kSmallT[t]] * 128;
      sm.M[t] = kRows[kSmallT[t]];
    }
    gemm_small<<<dim3(157, 5), 256, 0, stream>>>(sm, doRelu);

    VisitMeta vm;
    for (int q = 0; q < 5; ++q) {
      vm.xs[q] = xc + (size_t)kOff[kSmallT[q]] * 128;  // pv,sv,prv,dv,drv srcs
      vm.rp[q] = prefix + kCbcVisit[q];
    }
    gemm_visit<<<dim3(782), 256, 0, stream>>>(
        vm, xc + (size_t)kOff[1] * 128, esrc, LB, LB + 262144,
        xn + (size_t)kOff[1] * 128, NVISIT, doRelu);

    float* tmp = xc; xc = xn; xn = tmp;
  }

  const int ML = 200000;
  gemm_cls<<<dim3((ML + 127) / 128), 256, 0, stream>>>(
      xc + (size_t)kOff[1] * 128, xc + (size_t)kOff[5] * 128, eli,
      cw1, cb1, cw2, cb2, ylab, (float*)d_out, (float*)d_out + 1, ML);
}

// Round 3
// 2013.697 us; speedup vs baseline: 2.4776x; 1.5703x over previous
//
#include <hip/hip_runtime.h>
#include <cmath>

// ---------------------------------------------------------------------------
// Hetero-SAGE GNN (4 layers, 10 relations, D=128) + edge classifier. fp32.
// R3 restructure ("transform before aggregate", mean is linear):
//   visit-dst: Y_r = x_src @ Wl_r (srcs are the 46k small-type rows), then
//     xn[visit] = x_v @ SumWr + Sumb  (plain GEMM)  += sum_r mean_r(Y_r)
//     (agg_visit walks each edge list ONCE at full occupancy), then ReLU.
//   small-dst: aggregate-first (means over x_v), merged K=256 GEMM (as R2).
// GEMM FLOPs/layer: 2.27e10 -> 7.8e9. Y reuses the mean buffer.
// ---------------------------------------------------------------------------

#define NREL 10
static const int kCbc[NREL] = {0, 100000, 120000, 124000, 224000,
                               232000, 332000, 342000, 442000, 446000};
static const int kEh[NREL]  = {100000, 100000, 300000, 300000, 200000,
                               200000, 250000, 250000, 300000, 300000};
#define NCOUNTS 546000
#define NEDGES  2300000
#define NVISIT  100000
#define PL 180992  // per-layer Bcat floats: 16384 SumWr + 5*32768 stacks + 128 + 640

struct RelMeta { const int* ei[NREL]; int E[NREL]; int cbc[NREL]; };
struct GatherMeta { const float* emb[6]; const int* nid[6]; int rows[6]; int off[6]; };
struct AggMeta { const int* rp[5]; float* mean[5]; int M[5]; };
struct SmallMeta { const float* mean[5]; const float* xdst[5];
                   const float* B[5]; const float* bias[5];
                   float* out[5]; int M[5]; };
struct TransMeta { const float* A[6]; const float* B[6]; const float* bias[6];
                   float* out[6]; int M[6]; };
struct VAggMeta { const int* rp[5]; const float* Y[5]; };

// ---------------- init gather: x[off+i] = emb[nid[i]] ----------------------
__global__ __launch_bounds__(256) void gather_all(GatherMeta g, float* __restrict__ x) {
  int t = blockIdx.y;
  int i = blockIdx.x * 256 + threadIdx.x;
  if (i >= g.rows[t] * 32) return;
  int row = i >> 5, q = i & 31;
  int s = g.nid[t][row];
  *(float4*)(x + (size_t)(g.off[t] + row) * 128 + q * 4) =
      *(const float4*)(g.emb[t] + (size_t)s * 128 + q * 4);
}

// ---------------- CSR build ------------------------------------------------
__global__ __launch_bounds__(256) void hist_kernel(RelMeta m, int* __restrict__ counts) {
  int r = blockIdx.y;
  int e = blockIdx.x * 256 + threadIdx.x;
  if (e >= m.E[r]) return;
  int c = m.ei[r][m.E[r] + e];
  atomicAdd(&counts[m.cbc[r] + c], 1);
}

__global__ __launch_bounds__(1024) void scan1(const int* __restrict__ counts,
                                              int* __restrict__ partials) {
  __shared__ int s[1024];
  int i = blockIdx.x * 1024 + threadIdx.x;
  s[threadIdx.x] = (i < NCOUNTS) ? counts[i] : 0;
  __syncthreads();
  for (int off = 512; off > 0; off >>= 1) {
    if (threadIdx.x < off) s[threadIdx.x] += s[threadIdx.x + off];
    __syncthreads();
  }
  if (threadIdx.x == 0) partials[blockIdx.x] = s[0];
}

__global__ __launch_bounds__(1024) void scan2(int* __restrict__ partials, int nb) {
  __shared__ int s[1024];
  int t = threadIdx.x;
  int v = (t < nb) ? partials[t] : 0;
  s[t] = v;
  __syncthreads();
  for (int off = 1; off < 1024; off <<= 1) {
    int add = (t >= off) ? s[t - off] : 0;
    __syncthreads();
    s[t] += add;
    __syncthreads();
  }
  if (t < nb) partials[t] = s[t] - v;  // exclusive
}

__global__ __launch_bounds__(1024) void scan3(int* __restrict__ counts,
                                              int* __restrict__ prefix,
                                              const int* __restrict__ partials) {
  __shared__ int s[1024];
  int t = threadIdx.x;
  int i = blockIdx.x * 1024 + t;
  int v = (i < NCOUNTS) ? counts[i] : 0;
  s[t] = v;
  __syncthreads();
  for (int off = 1; off < 1024; off <<= 1) {
    int add = (t >= off) ? s[t - off] : 0;
    __syncthreads();
    s[t] += add;
    __syncthreads();
  }
  int P = partials[blockIdx.x] + s[t] - v;
  if (i < NCOUNTS) { prefix[i] = P; counts[i] = P; /* cursor */ }
  if (blockIdx.x == 0 && t == 0) prefix[NCOUNTS] = NEDGES;
}

__global__ __launch_bounds__(256) void scatter_kernel(RelMeta m, int* __restrict__ cursor,
                                                      int* __restrict__ esrc) {
  int r = blockIdx.y;
  int e = blockIdx.x * 256 + threadIdx.x;
  if (e >= m.E[r]) return;
  const int* ei = m.ei[r];
  int c = ei[m.E[r] + e];
  int pos = atomicAdd(&cursor[m.cbc[r] + c], 1);
  esrc[pos] = ei[e];
}

// ---------------- stacked B / bias prep ------------------------------------
// per layer: [0,16384): SumWr (visit); [16384,180224): small [Wl;Wr] stacks;
//            [180224,180352): visit bias = sum b; [180352,180992): small biases
__global__ __launch_bounds__(256) void prep_B(const float* __restrict__ W_l,
                                              const float* __restrict__ b_l,
                                              const float* __restrict__ W_r,
                                              float* __restrict__ Bcat) {
  const int visitRel[5] = {0, 3, 5, 7, 9};
  const int inRel[5] = {1, 2, 4, 6, 8};
  int gid = blockIdx.x * 256 + threadIdx.x;
  if (gid >= 4 * PL) return;
  int l = gid / PL, o = gid % PL;
  float val;
  if (o < 16384) {
    val = 0.f;
    #pragma unroll
    for (int q = 0; q < 5; ++q)
      val += W_r[(size_t)(l * 10 + visitRel[q]) * 16384 + o];
  } else if (o < 180224) {
    int o2 = o - 16384;
    int t = o2 >> 15, o3 = o2 & 32767;
    int row = o3 >> 7, c = o3 & 127;
    int r = inRel[t];
    val = (row < 128) ? W_l[(size_t)(l * 10 + r) * 16384 + row * 128 + c]
                      : W_r[(size_t)(l * 10 + r) * 16384 + (row - 128) * 128 + c];
  } else if (o < 180352) {
    int c = o - 180224;
    val = 0.f;
    #pragma unroll
    for (int q = 0; q < 5; ++q) val += b_l[(l * 10 + visitRel[q]) * 128 + c];
  } else {
    int t = (o - 180352) >> 7, c = (o - 180352) & 127;
    val = b_l[(l * 10 + inRel[t]) * 128 + c];
  }
  Bcat[(size_t)l * PL + o] = val;
}

// ---------------- mean aggregation (x_v -> small-dst means) ----------------
__global__ __launch_bounds__(256) void agg_small(AggMeta m, const float* __restrict__ xv,
                                                 const int* __restrict__ esrc) {
  int t = blockIdx.y;
  int row = blockIdx.x * 8 + (threadIdx.x >> 5);
  if (row >= m.M[t]) return;
  int q = threadIdx.x & 31;
  const int* rp = m.rp[t];
  int e0 = rp[row], e1 = rp[row + 1];
  float4 acc = make_float4(0.f, 0.f, 0.f, 0.f);
  for (int e = e0; e < e1; ++e) {
    int s = esrc[e];
    float4 v = *(const float4*)(xv + (size_t)s * 128 + q * 4);
    acc.x += v.x; acc.y += v.y; acc.z += v.z; acc.w += v.w;
  }
  float inv = (e1 > e0) ? 1.f / (float)(e1 - e0) : 0.f;
  acc.x *= inv; acc.y *= inv; acc.z *= inv; acc.w *= inv;
  *(float4*)(m.mean[t] + (size_t)row * 128 + q * 4) = acc;
}

// ---------------- visit aggregation: xn_v += sum_r mean_r(Y_r), relu -------
__global__ __launch_bounds__(256) void agg_visit(VAggMeta va, const int* __restrict__ esrc,
                                                 float* __restrict__ xnv, int doRelu) {
  int row = blockIdx.x * 8 + (threadIdx.x >> 5);
  if (row >= NVISIT) return;
  int q = threadIdx.x & 31;
  float* op = xnv + (size_t)row * 128 + q * 4;
  float4 acc = *(float4*)op;
  #pragma unroll
  for (int r = 0; r < 5; ++r) {
    int e0 = va.rp[r][row], e1 = va.rp[r][row + 1];
    if (e1 > e0) {
      const float* Y = va.Y[r];
      float4 s = make_float4(0.f, 0.f, 0.f, 0.f);
      for (int e = e0; e < e1; ++e) {
        int si = esrc[e];
        float4 v = *(const float4*)(Y + (size_t)si * 128 + q * 4);
        s.x += v.x; s.y += v.y; s.z += v.z; s.w += v.w;
      }
      float inv = 1.f / (float)(e1 - e0);
      acc.x += s.x * inv; acc.y += s.y * inv;
      acc.z += s.z * inv; acc.w += s.w * inv;
    }
  }
  if (doRelu) {
    acc.x = fmaxf(acc.x, 0.f); acc.y = fmaxf(acc.y, 0.f);
    acc.z = fmaxf(acc.z, 0.f); acc.w = fmaxf(acc.w, 0.f);
  }
  *(float4*)op = acc;
}

// ---------------- merged K=128 GEMMs: Y_r = x_src@Wl_r ; xn_v = x_v@SumWr+b -
__global__ __launch_bounds__(256, 2) void gemm_trans(TransMeta tm) {
  int t = blockIdx.y;
  int M = tm.M[t];
  int blockRow = blockIdx.x * 128;
  if (blockRow >= M) return;
  __shared__ float As[16][128];
  __shared__ float Bs[16][128];
  int tid = threadIdx.x;
  int tx = tid & 15, ty = tid >> 4;
  const float* A = tm.A[t];
  const float* B = tm.B[t];
  float acc[8][8];
  #pragma unroll
  for (int i = 0; i < 8; ++i)
    #pragma unroll
    for (int j = 0; j < 8; ++j) acc[i][j] = 0.f;

  for (int kk = 0; kk < 8; ++kk) {
    int kb = kk * 16;
    #pragma unroll
    for (int i = 0; i < 2; ++i) {
      int f = tid * 2 + i;
      int rr = f >> 2, qc = f & 3;
      int gr = blockRow + rr;
      float4 v = make_float4(0.f, 0.f, 0.f, 0.f);
      if (gr < M) v = *(const float4*)(A + (size_t)gr * 128 + kb + qc * 4);
      As[qc * 4 + 0][rr] = v.x; As[qc * 4 + 1][rr] = v.y;
      As[qc * 4 + 2][rr] = v.z; As[qc * 4 + 3][rr] = v.w;
      int kr = f >> 5, c4 = f & 31;
      *(float4*)&Bs[kr][c4 * 4] =
          *(const float4*)(B + (size_t)(kb + kr) * 128 + c4 * 4);
    }
    __syncthreads();
    #pragma unroll
    for (int k = 0; k < 16; ++k) {
      float a[8], b[8];
      *(float4*)&a[0] = *(float4*)&As[k][ty * 8];
      *(float4*)&a[4] = *(float4*)&As[k][ty * 8 + 4];
      *(float4*)&b[0] = *(float4*)&Bs[k][tx * 8];
      *(float4*)&b[4] = *(float4*)&Bs[k][tx * 8 + 4];
      #pragma unroll
      for (int i = 0; i < 8; ++i)
        #pragma unroll
        for (int j = 0; j < 8; ++j) acc[i][j] += a[i] * b[j];
    }
    __syncthreads();
  }

  float bv[8];
  #pragma unroll
  for (int j = 0; j < 8; ++j) bv[j] = 0.f;
  if (tm.bias[t]) {
    *(float4*)&bv[0] = *(const float4*)(tm.bias[t] + tx * 8);
    *(float4*)&bv[4] = *(const float4*)(tm.bias[t] + tx * 8 + 4);
  }
  #pragma unroll
  for (int i = 0; i < 8; ++i) {
    int gr = blockRow + ty * 8 + i;
    if (gr >= M) continue;
    float* o = tm.out[t] + (size_t)gr * 128 + tx * 8;
    *(float4*)o = make_float4(acc[i][0] + bv[0], acc[i][1] + bv[1],
                              acc[i][2] + bv[2], acc[i][3] + bv[3]);
    *(float4*)(o + 4) = make_float4(acc[i][4] + bv[4], acc[i][5] + bv[5],
                                    acc[i][6] + bv[6], acc[i][7] + bv[7]);
  }
}

// ---------------- small-type GEMM (merged, write-only): M x 256 x 128 ------
__global__ __launch_bounds__(256, 2) void gemm_small(SmallMeta sm, int doRelu) {
  int t = blockIdx.y;
  int M = sm.M[t];
  int blockRow = blockIdx.x * 128;
  if (blockRow >= M) return;
  __shared__ float As[16][128];
  __shared__ float Bs[16][128];
  int tid = threadIdx.x;
  int tx = tid & 15, ty = tid >> 4;
  const float* B = sm.B[t];
  float acc[8][8];
  #pragma unroll
  for (int i = 0; i < 8; ++i)
    #pragma unroll
    for (int j = 0; j < 8; ++j) acc[i][j] = 0.f;

  for (int kk = 0; kk < 16; ++kk) {
    const float* A = (kk < 8) ? sm.mean[t] : sm.xdst[t];
    int kb = (kk & 7) * 16;
    #pragma unroll
    for (int i = 0; i < 2; ++i) {
      int f = tid * 2 + i;
      int rr = f >> 2, qc = f & 3;
      int gr = blockRow + rr;
      float4 v = make_float4(0.f, 0.f, 0.f, 0.f);
      if (gr < M) v = *(const float4*)(A + (size_t)gr * 128 + kb + qc * 4);
      As[qc * 4 + 0][rr] = v.x; As[qc * 4 + 1][rr] = v.y;
      As[qc * 4 + 2][rr] = v.z; As[qc * 4 + 3][rr] = v.w;
      int kr = f >> 5, c4 = f & 31;
      *(float4*)&Bs[kr][c4 * 4] =
          *(const float4*)(B + (size_t)(kk * 16 + kr) * 128 + c4 * 4);
    }
    __syncthreads();
    #pragma unroll
    for (int k = 0; k < 16; ++k) {
      float a[8], b[8];
      *(float4*)&a[0] = *(float4*)&As[k][ty * 8];
      *(float4*)&a[4] = *(float4*)&As[k][ty * 8 + 4];
      *(float4*)&b[0] = *(float4*)&Bs[k][tx * 8];
      *(float4*)&b[4] = *(float4*)&Bs[k][tx * 8 + 4];
      #pragma unroll
      for (int i = 0; i < 8; ++i)
        #pragma unroll
        for (int j = 0; j < 8; ++j) acc[i][j] += a[i] * b[j];
    }
    __syncthreads();
  }

  float bv[8];
  *(float4*)&bv[0] = *(const float4*)(sm.bias[t] + tx * 8);
  *(float4*)&bv[4] = *(const float4*)(sm.bias[t] + tx * 8 + 4);
  #pragma unroll
  for (int i = 0; i < 8; ++i) {
    int gr = blockRow + ty * 8 + i;
    if (gr >= M) continue;
    float v[8];
    #pragma unroll
    for (int j = 0; j < 8; ++j) {
      v[j] = acc[i][j] + bv[j];
      if (doRelu) v[j] = fmaxf(v[j], 0.f);
    }
    float* o = sm.out[t] + (size_t)gr * 128 + tx * 8;
    *(float4*)o = make_float4(v[0], v[1], v[2], v[3]);
    *(float4*)(o + 4) = make_float4(v[4], v[5], v[6], v[7]);
  }
}

// ---------------- fused classifier -----------------------------------------
__global__ __launch_bounds__(256, 2) void gemm_cls(
    const float* __restrict__ xv, const float* __restrict__ xd,
    const int* __restrict__ eli, const float* __restrict__ W1,
    const float* __restrict__ b1, const float* __restrict__ w2,
    const float* __restrict__ b2, const float* __restrict__ y,
    float* __restrict__ lossOut, float* __restrict__ pred, int M) {
  __shared__ float As[16][128];
  __shared__ float Bs[16][128];
  __shared__ int idxA[128];
  __shared__ int idxB[128];
  int tid = threadIdx.x;
  int tx = tid & 15, ty = tid >> 4;
  int blockRow = blockIdx.x * 128;
  if (tid < 128) {
    int gr = blockRow + tid;
    idxA[tid] = (gr < M) ? eli[gr] : 0;
  } else {
    int t2 = tid - 128;
    int gr = blockRow + t2;
    idxB[t2] = (gr < M) ? eli[M + gr] : 0;
  }
  float acc[8][8];
  #pragma unroll
  for (int i = 0; i < 8; ++i)
    #pragma unroll
    for (int j = 0; j < 8; ++j) acc[i][j] = 0.f;
  __syncthreads();

  for (int kk = 0; kk < 16; ++kk) {
    int kb = (kk & 7) * 16;
    #pragma unroll
    for (int i = 0; i < 2; ++i) {
      int f = tid * 2 + i;
      int rr = f >> 2, qc = f & 3;
      const float* src = (kk < 8) ? (xv + (size_t)idxA[rr] * 128)
                                  : (xd + (size_t)idxB[rr] * 128);
      float4 v = *(const float4*)(src + kb + qc * 4);
      As[qc * 4 + 0][rr] = v.x; As[qc * 4 + 1][rr] = v.y;
      As[qc * 4 + 2][rr] = v.z; As[qc * 4 + 3][rr] = v.w;
      int kr = f >> 5, c4 = f & 31;
      *(float4*)&Bs[kr][c4 * 4] =
          *(const float4*)(W1 + (size_t)(kk * 16 + kr) * 128 + c4 * 4);
    }
    __syncthreads();
    #pragma unroll
    for (int k = 0; k < 16; ++k) {
      float a[8], b[8];
      *(float4*)&a[0] = *(float4*)&As[k][ty * 8];
      *(float4*)&a[4] = *(float4*)&As[k][ty * 8 + 4];
      *(float4*)&b[0] = *(float4*)&Bs[k][tx * 8];
      *(float4*)&b[4] = *(float4*)&Bs[k][tx * 8 + 4];
      #pragma unroll
      for (int i = 0; i < 8; ++i)
        #pragma unroll
        for (int j = 0; j < 8; ++j) acc[i][j] += a[i] * b[j];
    }
    __syncthreads();
  }

  float b1v[8], w2v[8];
  *(float4*)&b1v[0] = *(const float4*)(b1 + tx * 8);
  *(float4*)&b1v[4] = *(const float4*)(b1 + tx * 8 + 4);
  *(float4*)&w2v[0] = *(const float4*)(w2 + tx * 8);
  *(float4*)&w2v[4] = *(const float4*)(w2 + tx * 8 + 4);
  float b2v = b2[0];
  float local = 0.f;
  #pragma unroll
  for (int i = 0; i < 8; ++i) {
    float p = 0.f;
    #pragma unroll
    for (int j = 0; j < 8; ++j) {
      float h = fmaxf(acc[i][j] + b1v[j], 0.f);
      p += h * w2v[j];
    }
    p += __shfl_xor(p, 1);
    p += __shfl_xor(p, 2);
    p += __shfl_xor(p, 4);
    p += __shfl_xor(p, 8);
    int gr = blockRow + ty * 8 + i;
    if (tx == 0 && gr < M) {
      float z = p + b2v;
      pred[gr] = z;
      float lv = fmaxf(z, 0.f) + log1pf(expf(-fabsf(z))) - z * y[gr];
      local += lv;
    }
  }
  __shared__ float red[16];
  if (tx == 0) red[ty] = local;
  __syncthreads();
  if (tid == 0) {
    float s = 0.f;
    #pragma unroll
    for (int i = 0; i < 16; ++i) s += red[i];
    atomicAdd(lossOut, s * (1.0f / 200000.0f));
  }
}

// ---------------------------------------------------------------------------
extern "C" void kernel_launch(void* const* d_in, const int* in_sizes, int n_in,
                              void* d_out, int out_size, void* d_ws, size_t ws_size,
                              hipStream_t stream) {
  static const int kRows[6] = {20000, 100000, 4000, 8000, 10000, 4000};
  static const int kOff[6]  = {0, 20000, 120000, 124000, 132000, 142000};
  static const int kSmallT[5]   = {0, 2, 3, 4, 5};                         // patient,symptom,proc,disease,drug
  static const int kVisitRel[5] = {0, 3, 5, 7, 9};                         // pv,sv,prv,dv,drv
  static const int kCbcIn[5]    = {100000, 120000, 224000, 332000, 442000}; // vp,vs,vpr,vd,vdr
  static const int kCbcVisit[5] = {0, 124000, 232000, 342000, 446000};      // pv,sv,prv,dv,drv
  static const int kYOff[5]     = {0, 20000, 24000, 32000, 42000};          // by src rows

  const float* W_l = (const float*)d_in[22];
  const float* b_l = (const float*)d_in[23];
  const float* W_r = (const float*)d_in[24];
  const float* cw1 = (const float*)d_in[25];
  const float* cb1 = (const float*)d_in[26];
  const float* cw2 = (const float*)d_in[27];
  const float* cb2 = (const float*)d_in[28];
  const int* eli = (const int*)d_in[29];
  const float* ylab = (const float*)d_in[30];

  // workspace layout
  const size_t XFLOATS = 146000UL * 128UL;           // 18,688,000 floats
  float* xA = (float*)d_ws;
  float* xB = xA + XFLOATS;
  float* meanS = xB + XFLOATS;                       // 46000*128 (means; reused as Y)
  int* prefix = (int*)(meanS + 46000UL * 128UL);     // 546,004 ints
  int* counts = prefix + 546004;                     // 546,000 (doubles as cursor)
  int* esrc = counts + NCOUNTS;                      // 2,300,000
  int* partials = esrc + NEDGES;                     // 1,024
  float* Bcat = (float*)(partials + 1024);           // 4 * PL floats

  RelMeta rm;
  for (int r = 0; r < NREL; ++r) {
    rm.ei[r] = (const int*)d_in[12 + r];
    rm.E[r] = kEh[r];
    rm.cbc[r] = kCbc[r];
  }

  hipMemsetAsync(counts, 0, NCOUNTS * sizeof(int), stream);
  hipMemsetAsync(d_out, 0, sizeof(float), stream);

  prep_B<<<(4 * PL + 255) / 256, 256, 0, stream>>>(W_l, b_l, W_r, Bcat);

  GatherMeta gm;
  for (int t = 0; t < 6; ++t) {
    gm.nid[t] = (const int*)d_in[2 * t];
    gm.emb[t] = (const float*)d_in[2 * t + 1];
    gm.rows[t] = kRows[t];
    gm.off[t] = kOff[t];
  }
  gather_all<<<dim3(12500, 6), 256, 0, stream>>>(gm, xA);

  dim3 egrid(1172, NREL);
  hist_kernel<<<egrid, 256, 0, stream>>>(rm, counts);
  scan1<<<534, 1024, 0, stream>>>(counts, partials);
  scan2<<<1, 1024, 0, stream>>>(partials, 534);
  scan3<<<534, 1024, 0, stream>>>(counts, prefix, partials);
  scatter_kernel<<<egrid, 256, 0, stream>>>(rm, counts, esrc);

  float* xc = xA;
  float* xn = xB;
  for (int l = 0; l < 4; ++l) {
    int doRelu = (l < 3);
    float* LB = Bcat + (size_t)l * PL;

    // 1) means of x_v for small-dst relations
    AggMeta am;
    for (int t = 0; t < 5; ++t) {
      am.rp[t] = prefix + kCbcIn[t];
      am.mean[t] = meanS + (size_t)kYOff[t] * 128;
      am.M[t] = kRows[kSmallT[t]];
    }
    agg_small<<<dim3(2500, 5), 256, 0, stream>>>(am, xc + (size_t)kOff[1] * 128, esrc);

    // 2) small-dst outputs: [mean | x_dst] @ [Wl;Wr] + b (+relu)
    SmallMeta sm;
    for (int t = 0; t < 5; ++t) {
      sm.mean[t] = meanS + (size_t)kYOff[t] * 128;
      sm.xdst[t] = xc + (size_t)kOff[kSmallT[t]] * 128;
      sm.B[t] = LB + 16384 + (size_t)t * 32768;
      sm.bias[t] = LB + 180352 + t * 128;
      sm.out[t] = xn + (size_t)kOff[kSmallT[t]] * 128;
      sm.M[t] = kRows[kSmallT[t]];
    }
    gemm_small<<<dim3(157, 5), 256, 0, stream>>>(sm, doRelu);

    // 3) Y_r = x_src @ Wl_r (into meanS, now dead) ; xn_v = x_v @ SumWr + Sumb
    TransMeta tm;
    for (int q = 0; q < 5; ++q) {
      tm.A[q] = xc + (size_t)kOff[kSmallT[q]] * 128;
      tm.B[q] = W_l + (size_t)(l * 10 + kVisitRel[q]) * 16384;
      tm.bias[q] = nullptr;
      tm.out[q] = meanS + (size_t)kYOff[q] * 128;
      tm.M[q] = kRows[kSmallT[q]];
    }
    tm.A[5] = xc + (size_t)kOff[1] * 128;
    tm.B[5] = LB;                 // SumWr
    tm.bias[5] = LB + 180224;     // Sum b
    tm.out[5] = xn + (size_t)kOff[1] * 128;
    tm.M[5] = NVISIT;
    gemm_trans<<<dim3(782, 6), 256, 0, stream>>>(tm);

    // 4) xn_v += sum_r mean_r(Y_r); relu
    VAggMeta va;
    for (int q = 0; q < 5; ++q) {
      va.rp[q] = prefix + kCbcVisit[q];
      va.Y[q] = meanS + (size_t)kYOff[q] * 128;
    }
    agg_visit<<<dim3(12500), 256, 0, stream>>>(va, esrc, xn + (size_t)kOff[1] * 128, doRelu);

    float* tmp = xc; xc = xn; xn = tmp;
  }

  const int ML = 200000;
  gemm_cls<<<dim3((ML + 127) / 128), 256, 0, stream>>>(
      xc + (size_t)kOff[1] * 128, xc + (size_t)kOff[5] * 128, eli,
      cw1, cb1, cw2, cb2, ylab, (float*)d_out, (float*)d_out + 1, ML);
}

// Round 4
// 1582.506 us; speedup vs baseline: 3.1526x; 1.2725x over previous
//
#include <hip/hip_runtime.h>
#include <cmath>

// ---------------------------------------------------------------------------
// Hetero-SAGE GNN (4 layers, 10 relations, D=128) + edge classifier.
// R4: all GEMMs moved to MFMA f16x3 split (AhBh + AhBl + AlBh, fp32 acc,
// ~22-bit effective mantissa). Weights pre-split+transposed to [n][k] f16
// tables by prep kernel (B-frags straight from L2, no LDS for B). A staged
// through LDS as split f16 halves. Aggregation stays fp32 (exact).
// Verified MFMA layouts: A[m=lane&15][k=quad*8+j]; B[k=quad*8+j][n=lane&15];
// C col=lane&15, row=quad*4+reg.
// ---------------------------------------------------------------------------

typedef _Float16 f16x8 __attribute__((ext_vector_type(8)));
typedef _Float16 f16x4 __attribute__((ext_vector_type(4)));
typedef float f32x4 __attribute__((ext_vector_type(4)));

#define NREL 10
static const int kCbc[NREL] = {0, 100000, 120000, 124000, 224000,
                               232000, 332000, 342000, 442000, 446000};
static const int kEh[NREL]  = {100000, 100000, 300000, 300000, 200000,
                               200000, 250000, 250000, 300000, 300000};
#define NCOUNTS 546000
#define NEDGES  2300000
#define NVISIT  100000
// Wt (split f16 weight tables), element offsets (_Float16 units):
//  per layer l at l*PLW:
//   smalls t (t=0..4):  t*67584          [2][128][264]  (K=256: [Wl_in;Wr_in])
//   trans  q (q=0..4):  337920+q*34816   [2][128][136]  (K=128: Wl_visitRel)
//   SumWr:              512000           [2][128][136]
//  cls W1 at 4*PLW: [2][128][264]
#define PLW 546816
#define WT_ELEMS (4 * PLW + 67584)

struct RelMeta { const int* ei[NREL]; int E[NREL]; int cbc[NREL]; };
struct GatherMeta { const float* emb[6]; const int* nid[6]; int rows[6]; int off[6]; };
struct AggMeta { const int* rp[5]; float* mean[5]; int M[5]; };
struct VAggMeta { const int* rp[5]; const float* Y[5]; };
struct MTask {
  const float* A0; const float* A1;   // A1 = rows for k in [128,256)
  const _Float16* W;                  // [2][128][Kpad], h-plane then l-plane
  const float* bias;                  // nullable
  float* out;
  int M, blkOff, K, relu;
};
struct MMeta { MTask t[6]; int nTasks; };

// ---------------- init gather ----------------------------------------------
__global__ __launch_bounds__(256) void gather_all(GatherMeta g, float* __restrict__ x) {
  int t = blockIdx.y;
  int i = blockIdx.x * 256 + threadIdx.x;
  if (i >= g.rows[t] * 32) return;
  int row = i >> 5, q = i & 31;
  int s = g.nid[t][row];
  *(float4*)(x + (size_t)(g.off[t] + row) * 128 + q * 4) =
      *(const float4*)(g.emb[t] + (size_t)s * 128 + q * 4);
}

// ---------------- CSR build ------------------------------------------------
__global__ __launch_bounds__(256) void hist_kernel(RelMeta m, int* __restrict__ counts) {
  int r = blockIdx.y;
  int e = blockIdx.x * 256 + threadIdx.x;
  if (e >= m.E[r]) return;
  int c = m.ei[r][m.E[r] + e];
  atomicAdd(&counts[m.cbc[r] + c], 1);
}

__global__ __launch_bounds__(1024) void scan1(const int* __restrict__ counts,
                                              int* __restrict__ partials) {
  __shared__ int s[1024];
  int i = blockIdx.x * 1024 + threadIdx.x;
  s[threadIdx.x] = (i < NCOUNTS) ? counts[i] : 0;
  __syncthreads();
  for (int off = 512; off > 0; off >>= 1) {
    if (threadIdx.x < off) s[threadIdx.x] += s[threadIdx.x + off];
    __syncthreads();
  }
  if (threadIdx.x == 0) partials[blockIdx.x] = s[0];
}

__global__ __launch_bounds__(1024) void scan2(int* __restrict__ partials, int nb) {
  __shared__ int s[1024];
  int t = threadIdx.x;
  int v = (t < nb) ? partials[t] : 0;
  s[t] = v;
  __syncthreads();
  for (int off = 1; off < 1024; off <<= 1) {
    int add = (t >= off) ? s[t - off] : 0;
    __syncthreads();
    s[t] += add;
    __syncthreads();
  }
  if (t < nb) partials[t] = s[t] - v;  // exclusive
}

__global__ __launch_bounds__(1024) void scan3(int* __restrict__ counts,
                                              int* __restrict__ prefix,
                                              const int* __restrict__ partials) {
  __shared__ int s[1024];
  int t = threadIdx.x;
  int i = blockIdx.x * 1024 + t;
  int v = (i < NCOUNTS) ? counts[i] : 0;
  s[t] = v;
  __syncthreads();
  for (int off = 1; off < 1024; off <<= 1) {
    int add = (t >= off) ? s[t - off] : 0;
    __syncthreads();
    s[t] += add;
    __syncthreads();
  }
  int P = partials[blockIdx.x] + s[t] - v;
  if (i < NCOUNTS) { prefix[i] = P; counts[i] = P; }
  if (blockIdx.x == 0 && t == 0) prefix[NCOUNTS] = NEDGES;
}

__global__ __launch_bounds__(256) void scatter_kernel(RelMeta m, int* __restrict__ cursor,
                                                      int* __restrict__ esrc) {
  int r = blockIdx.y;
  int e = blockIdx.x * 256 + threadIdx.x;
  if (e >= m.E[r]) return;
  const int* ei = m.ei[r];
  int c = ei[m.E[r] + e];
  int pos = atomicAdd(&cursor[m.cbc[r] + c], 1);
  esrc[pos] = ei[e];
}

// ---------------- weight split/transpose prep ------------------------------
__global__ __launch_bounds__(256) void prep_split(
    const float* __restrict__ W_l, const float* __restrict__ b_l,
    const float* __restrict__ W_r, const float* __restrict__ cw1,
    _Float16* __restrict__ Wt, float* __restrict__ visitSumB) {
  const int visitRel[5] = {0, 3, 5, 7, 9};
  const int inRel[5] = {1, 2, 4, 6, 8};
  int gid = blockIdx.x * 256 + threadIdx.x;
  // layer matrices: 4 * 262144 ; cls: 32768 ; visitSumB: 512
  if (gid < 1048576) {
    int l = gid >> 18, o = gid & 262143;
    float val; size_t base; int n, k, Kpad;
    if (o < 163840) {          // small stacks, K=256
      int t = o >> 15, e = o & 32767;
      k = e >> 7; n = e & 127; Kpad = 264;
      int r = inRel[t];
      val = (k < 128) ? W_l[(size_t)(l * 10 + r) * 16384 + k * 128 + n]
                      : W_r[(size_t)(l * 10 + r) * 16384 + (k - 128) * 128 + n];
      base = (size_t)l * PLW + t * 67584;
    } else if (o < 245760) {   // trans Wl, K=128
      int q = (o - 163840) >> 14, e = (o - 163840) & 16383;
      k = e >> 7; n = e & 127; Kpad = 136;
      val = W_l[(size_t)(l * 10 + visitRel[q]) * 16384 + k * 128 + n];
      base = (size_t)l * PLW + 337920 + q * 34816;
    } else {                   // SumWr, K=128
      int e = o - 245760;
      k = e >> 7; n = e & 127; Kpad = 136;
      val = 0.f;
      #pragma unroll
      for (int q = 0; q < 5; ++q)
        val += W_r[(size_t)(l * 10 + visitRel[q]) * 16384 + k * 128 + n];
      base = (size_t)l * PLW + 512000;
    }
    _Float16 h = (_Float16)val;
    _Float16 lo = (_Float16)(val - (float)h);
    Wt[base + (size_t)n * Kpad + k] = h;
    Wt[base + (size_t)(128 + n) * Kpad + k] = lo;
  } else if (gid < 1081344) {  // cls W1, K=256
    int e = gid - 1048576;
    int k = e >> 7, n = e & 127;
    float val = cw1[(size_t)k * 128 + n];
    _Float16 h = (_Float16)val;
    _Float16 lo = (_Float16)(val - (float)h);
    size_t base = (size_t)4 * PLW;
    Wt[base + (size_t)n * 264 + k] = h;
    Wt[base + (size_t)(128 + n) * 264 + k] = lo;
  } else if (gid < 1081856) {  // visit summed bias
    int e = gid - 1081344;
    int l = e >> 7, c = e & 127;
    float val = 0.f;
    #pragma unroll
    for (int q = 0; q < 5; ++q) val += b_l[(l * 10 + visitRel[q]) * 128 + c];
    visitSumB[e] = val;
  }
}

// ---------------- mean aggregation (x_v -> small-dst means) ----------------
__global__ __launch_bounds__(256) void agg_small(AggMeta m, const float* __restrict__ xv,
                                                 const int* __restrict__ esrc) {
  int t = blockIdx.y;
  int row = blockIdx.x * 8 + (threadIdx.x >> 5);
  if (row >= m.M[t]) return;
  int q = threadIdx.x & 31;
  const int* rp = m.rp[t];
  int e0 = rp[row], e1 = rp[row + 1];
  float4 acc = make_float4(0.f, 0.f, 0.f, 0.f);
  for (int e = e0; e < e1; ++e) {
    int s = esrc[e];
    float4 v = *(const float4*)(xv + (size_t)s * 128 + q * 4);
    acc.x += v.x; acc.y += v.y; acc.z += v.z; acc.w += v.w;
  }
  float inv = (e1 > e0) ? 1.f / (float)(e1 - e0) : 0.f;
  acc.x *= inv; acc.y *= inv; acc.z *= inv; acc.w *= inv;
  *(float4*)(m.mean[t] + (size_t)row * 128 + q * 4) = acc;
}

// ---------------- visit aggregation: xn_v += sum_r mean_r(Y_r), relu -------
__global__ __launch_bounds__(256) void agg_visit(VAggMeta va, const int* __restrict__ esrc,
                                                 float* __restrict__ xnv, int doRelu) {
  int row = blockIdx.x * 8 + (threadIdx.x >> 5);
  if (row >= NVISIT) return;
  int q = threadIdx.x & 31;
  float* op = xnv + (size_t)row * 128 + q * 4;
  float4 acc = *(float4*)op;
  #pragma unroll
  for (int r = 0; r < 5; ++r) {
    int e0 = va.rp[r][row], e1 = va.rp[r][row + 1];
    if (e1 > e0) {
      const float* Y = va.Y[r];
      float4 s = make_float4(0.f, 0.f, 0.f, 0.f);
      for (int e = e0; e < e1; ++e) {
        int si = esrc[e];
        float4 v = *(const float4*)(Y + (size_t)si * 128 + q * 4);
        s.x += v.x; s.y += v.y; s.z += v.z; s.w += v.w;
      }
      float inv = 1.f / (float)(e1 - e0);
      acc.x += s.x * inv; acc.y += s.y * inv;
      acc.z += s.z * inv; acc.w += s.w * inv;
    }
  }
  if (doRelu) {
    acc.x = fmaxf(acc.x, 0.f); acc.y = fmaxf(acc.y, 0.f);
    acc.z = fmaxf(acc.z, 0.f); acc.w = fmaxf(acc.w, 0.f);
  }
  *(float4*)op = acc;
}

// ---------------- MFMA f16x3 GEMM, multi-task ------------------------------
// BM=BN=128, BK=64, 256 thr = 4 waves (2x2 of 64x64), 16x16x32 tiles.
__global__ __launch_bounds__(256, 2) void mgemm(MMeta mm) {
  int b = blockIdx.x;
  int ti = 0;
  for (int i = 1; i < mm.nTasks; ++i) if (b >= mm.t[i].blkOff) ti = i;
  MTask tk = mm.t[ti];
  int blockRow = (b - tk.blkOff) * 128;
  int Kpad = tk.K + 8;

  __shared__ _Float16 Ash[2][128][72];
  int tid = threadIdx.x;
  int wave = tid >> 6, lane = tid & 63;
  int quad = lane >> 4, lm = lane & 15;
  int wr = wave >> 1, wc = wave & 1;

  f32x4 acc[4][4];
  #pragma unroll
  for (int i = 0; i < 4; ++i)
    #pragma unroll
    for (int j = 0; j < 4; ++j) acc[i][j] = (f32x4){0.f, 0.f, 0.f, 0.f};

  // B row pointers (n invariant over k)
  const _Float16* wrowH[4];
  const _Float16* wrowL[4];
  #pragma unroll
  for (int nt = 0; nt < 4; ++nt) {
    int n = wc * 64 + nt * 16 + lm;
    wrowH[nt] = tk.W + (size_t)n * Kpad;
    wrowL[nt] = tk.W + (size_t)(128 + n) * Kpad;
  }

  int sr = tid >> 1, sk = (tid & 1) * 32;  // staging: row, k-seg
  for (int k0 = 0; k0 < tk.K; k0 += 64) {
    const float* Asrc = (k0 < 128) ? tk.A0 : tk.A1;
    int ak0 = (k0 & 127) + sk;
    int gr = blockRow + sr;
    if (gr < tk.M) {
      const float* p = Asrc + (size_t)gr * 128 + ak0;
      #pragma unroll
      for (int c = 0; c < 8; ++c) {
        float4 v = *(const float4*)(p + c * 4);
        f16x4 hv, lv;
        hv[0] = (_Float16)v.x; hv[1] = (_Float16)v.y;
        hv[2] = (_Float16)v.z; hv[3] = (_Float16)v.w;
        lv[0] = (_Float16)(v.x - (float)hv[0]);
        lv[1] = (_Float16)(v.y - (float)hv[1]);
        lv[2] = (_Float16)(v.z - (float)hv[2]);
        lv[3] = (_Float16)(v.w - (float)hv[3]);
        *(f16x4*)&Ash[0][sr][sk + c * 4] = hv;
        *(f16x4*)&Ash[1][sr][sk + c * 4] = lv;
      }
    } else {
      f16x4 z = (f16x4){(_Float16)0.f, (_Float16)0.f, (_Float16)0.f, (_Float16)0.f};
      #pragma unroll
      for (int c = 0; c < 8; ++c) {
        *(f16x4*)&Ash[0][sr][sk + c * 4] = z;
        *(f16x4*)&Ash[1][sr][sk + c * 4] = z;
      }
    }
    __syncthreads();
    #pragma unroll
    for (int ks = 0; ks < 64; ks += 32) {
      int kf = k0 + ks + quad * 8;
      f16x8 bh[4], bl[4];
      #pragma unroll
      for (int nt = 0; nt < 4; ++nt) {
        bh[nt] = *(const f16x8*)(wrowH[nt] + kf);
        bl[nt] = *(const f16x8*)(wrowL[nt] + kf);
      }
      #pragma unroll
      for (int mt = 0; mt < 4; ++mt) {
        int r = wr * 64 + mt * 16 + lm;
        f16x8 ah = *(const f16x8*)&Ash[0][r][ks + quad * 8];
        f16x8 al = *(const f16x8*)&Ash[1][r][ks + quad * 8];
        #pragma unroll
        for (int nt = 0; nt < 4; ++nt) {
          acc[mt][nt] = __builtin_amdgcn_mfma_f32_16x16x32_f16(ah, bh[nt], acc[mt][nt], 0, 0, 0);
          acc[mt][nt] = __builtin_amdgcn_mfma_f32_16x16x32_f16(ah, bl[nt], acc[mt][nt], 0, 0, 0);
          acc[mt][nt] = __builtin_amdgcn_mfma_f32_16x16x32_f16(al, bh[nt], acc[mt][nt], 0, 0, 0);
        }
      }
    }
    __syncthreads();
  }

  // epilogue: row = wr*64+mt*16+quad*4+i ; col = wc*64+nt*16+lm
  float bv[4];
  #pragma unroll
  for (int nt = 0; nt < 4; ++nt)
    bv[nt] = tk.bias ? tk.bias[wc * 64 + nt * 16 + lm] : 0.f;
  #pragma unroll
  for (int mt = 0; mt < 4; ++mt) {
    #pragma unroll
    for (int i = 0; i < 4; ++i) {
      int grow = blockRow + wr * 64 + mt * 16 + quad * 4 + i;
      if (grow >= tk.M) continue;
      float* orow = tk.out + (size_t)grow * 128 + wc * 64 + lm;
      #pragma unroll
      for (int nt = 0; nt < 4; ++nt) {
        float v = acc[mt][nt][i] + bv[nt];
        if (tk.relu) v = fmaxf(v, 0.f);
        orow[nt * 16] = v;
      }
    }
  }
}

// ---------------- MFMA classifier ------------------------------------------
__global__ __launch_bounds__(256, 2) void mgemm_cls(
    const float* __restrict__ xv, const float* __restrict__ xd,
    const int* __restrict__ eli, const _Float16* __restrict__ W,  // [2][128][264]
    const float* __restrict__ b1, const float* __restrict__ w2,
    const float* __restrict__ b2, const float* __restrict__ y,
    float* __restrict__ lossOut, float* __restrict__ pred, int M) {
  __shared__ _Float16 Ash[2][128][72];
  __shared__ int idxA[128];
  __shared__ int idxB[128];
  __shared__ float predPart[128];
  __shared__ float redL[128];
  int tid = threadIdx.x;
  int wave = tid >> 6, lane = tid & 63;
  int quad = lane >> 4, lm = lane & 15;
  int wr = wave >> 1, wc = wave & 1;
  int blockRow = blockIdx.x * 128;
  if (tid < 128) {
    int gr = blockRow + tid;
    idxA[tid] = (gr < M) ? eli[gr] : 0;
  } else {
    int t2 = tid - 128;
    int gr = blockRow + t2;
    idxB[t2] = (gr < M) ? eli[M + gr] : 0;
  }
  f32x4 acc[4][4];
  #pragma unroll
  for (int i = 0; i < 4; ++i)
    #pragma unroll
    for (int j = 0; j < 4; ++j) acc[i][j] = (f32x4){0.f, 0.f, 0.f, 0.f};

  const _Float16* wrowH[4];
  const _Float16* wrowL[4];
  #pragma unroll
  for (int nt = 0; nt < 4; ++nt) {
    int n = wc * 64 + nt * 16 + lm;
    wrowH[nt] = W + (size_t)n * 264;
    wrowL[nt] = W + (size_t)(128 + n) * 264;
  }
  __syncthreads();

  int sr = tid >> 1, sk = (tid & 1) * 32;
  for (int k0 = 0; k0 < 256; k0 += 64) {
    const float* base = (k0 < 128) ? xv : xd;
    int srcRow = (k0 < 128) ? idxA[sr] : idxB[sr];
    const float* p = base + (size_t)srcRow * 128 + (k0 & 127) + sk;
    #pragma unroll
    for (int c = 0; c < 8; ++c) {
      float4 v = *(const float4*)(p + c * 4);
      f16x4 hv, lv;
      hv[0] = (_Float16)v.x; hv[1] = (_Float16)v.y;
      hv[2] = (_Float16)v.z; hv[3] = (_Float16)v.w;
      lv[0] = (_Float16)(v.x - (float)hv[0]);
      lv[1] = (_Float16)(v.y - (float)hv[1]);
      lv[2] = (_Float16)(v.z - (float)hv[2]);
      lv[3] = (_Float16)(v.w - (float)hv[3]);
      *(f16x4*)&Ash[0][sr][sk + c * 4] = hv;
      *(f16x4*)&Ash[1][sr][sk + c * 4] = lv;
    }
    __syncthreads();
    #pragma unroll
    for (int ks = 0; ks < 64; ks += 32) {
      int kf = k0 + ks + quad * 8;
      f16x8 bh[4], bl[4];
      #pragma unroll
      for (int nt = 0; nt < 4; ++nt) {
        bh[nt] = *(const f16x8*)(wrowH[nt] + kf);
        bl[nt] = *(const f16x8*)(wrowL[nt] + kf);
      }
      #pragma unroll
      for (int mt = 0; mt < 4; ++mt) {
        int r = wr * 64 + mt * 16 + lm;
        f16x8 ah = *(const f16x8*)&Ash[0][r][ks + quad * 8];
        f16x8 al = *(const f16x8*)&Ash[1][r][ks + quad * 8];
        #pragma unroll
        for (int nt = 0; nt < 4; ++nt) {
          acc[mt][nt] = __builtin_amdgcn_mfma_f32_16x16x32_f16(ah, bh[nt], acc[mt][nt], 0, 0, 0);
          acc[mt][nt] = __builtin_amdgcn_mfma_f32_16x16x32_f16(ah, bl[nt], acc[mt][nt], 0, 0, 0);
          acc[mt][nt] = __builtin_amdgcn_mfma_f32_16x16x32_f16(al, bh[nt], acc[mt][nt], 0, 0, 0);
        }
      }
    }
    __syncthreads();
  }

  // epilogue: h = relu(acc + b1[col]); row partial = sum_col h*w2[col]
  float b1v[4], w2v[4];
  #pragma unroll
  for (int nt = 0; nt < 4; ++nt) {
    int col = wc * 64 + nt * 16 + lm;
    b1v[nt] = b1[col];
    w2v[nt] = w2[col];
  }
  float rowp[4][4];  // [mt][i]
  #pragma unroll
  for (int mt = 0; mt < 4; ++mt)
    #pragma unroll
    for (int i = 0; i < 4; ++i) {
      float p = 0.f;
      #pragma unroll
      for (int nt = 0; nt < 4; ++nt)
        p += fmaxf(acc[mt][nt][i] + b1v[nt], 0.f) * w2v[nt];
      // reduce over the 16 lanes of this quad-group (cols)
      p += __shfl_xor(p, 1);
      p += __shfl_xor(p, 2);
      p += __shfl_xor(p, 4);
      p += __shfl_xor(p, 8);
      rowp[mt][i] = p;
    }
  // combine the two column-wave halves via LDS
  if (wc == 0 && lm == 0) {
    #pragma unroll
    for (int mt = 0; mt < 4; ++mt)
      #pragma unroll
      for (int i = 0; i < 4; ++i)
        predPart[wr * 64 + mt * 16 + quad * 4 + i] = rowp[mt][i];
  }
  __syncthreads();
  if (wc == 1 && lm == 0) {
    #pragma unroll
    for (int mt = 0; mt < 4; ++mt)
      #pragma unroll
      for (int i = 0; i < 4; ++i)
        predPart[wr * 64 + mt * 16 + quad * 4 + i] += rowp[mt][i];
  }
  __syncthreads();
  if (tid < 128) {
    int gr = blockRow + tid;
    float lv = 0.f;
    if (gr < M) {
      float z = predPart[tid] + b2[0];
      pred[gr] = z;
      lv = fmaxf(z, 0.f) + log1pf(expf(-fabsf(z))) - z * y[gr];
    }
    redL[tid] = lv;
  }
  __syncthreads();
  if (tid == 0) {
    float s = 0.f;
    for (int i = 0; i < 128; ++i) s += redL[i];
    atomicAdd(lossOut, s * (1.0f / 200000.0f));
  }
}

// ---------------------------------------------------------------------------
extern "C" void kernel_launch(void* const* d_in, const int* in_sizes, int n_in,
                              void* d_out, int out_size, void* d_ws, size_t ws_size,
                              hipStream_t stream) {
  static const int kRows[6] = {20000, 100000, 4000, 8000, 10000, 4000};
  static const int kOff[6]  = {0, 20000, 120000, 124000, 132000, 142000};
  static const int kSmallT[5]   = {0, 2, 3, 4, 5};
  static const int kInRel[5]    = {1, 2, 4, 6, 8};
  static const int kCbcIn[5]    = {100000, 120000, 224000, 332000, 442000};
  static const int kCbcVisit[5] = {0, 124000, 232000, 342000, 446000};
  static const int kYOff[5]     = {0, 20000, 24000, 32000, 42000};
  static const int kNb[5]       = {157, 32, 63, 79, 32};   // ceil(M/128)
  static const int kBOff[5]     = {0, 157, 189, 252, 331}; // prefix of kNb

  const float* W_l = (const float*)d_in[22];
  const float* b_l = (const float*)d_in[23];
  const float* W_r = (const float*)d_in[24];
  const float* cw1 = (const float*)d_in[25];
  const float* cb1 = (const float*)d_in[26];
  const float* cw2 = (const float*)d_in[27];
  const float* cb2 = (const float*)d_in[28];
  const int* eli = (const int*)d_in[29];
  const float* ylab = (const float*)d_in[30];

  // workspace layout (float units unless noted)
  const size_t XFLOATS = 146000UL * 128UL;           // 18,688,000
  float* xA = (float*)d_ws;
  float* xB = xA + XFLOATS;
  float* meanS = xB + XFLOATS;                       // 46000*128 (means / Y)
  int* prefix = (int*)(meanS + 46000UL * 128UL);     // 546,004
  int* counts = prefix + 546004;                     // 546,000
  int* esrc = counts + NCOUNTS;                      // 2,300,000
  int* partials = esrc + NEDGES;                     // 1,024
  float* visitSumB = (float*)(partials + 1024);      // 512
  _Float16* Wt = (_Float16*)(visitSumB + 512);       // WT_ELEMS (16B-aligned)

  RelMeta rm;
  for (int r = 0; r < NREL; ++r) {
    rm.ei[r] = (const int*)d_in[12 + r];
    rm.E[r] = kEh[r];
    rm.cbc[r] = kCbc[r];
  }

  hipMemsetAsync(counts, 0, NCOUNTS * sizeof(int), stream);
  hipMemsetAsync(d_out, 0, sizeof(float), stream);

  prep_split<<<(1081856 + 255) / 256, 256, 0, stream>>>(W_l, b_l, W_r, cw1, Wt, visitSumB);

  GatherMeta gm;
  for (int t = 0; t < 6; ++t) {
    gm.nid[t] = (const int*)d_in[2 * t];
    gm.emb[t] = (const float*)d_in[2 * t + 1];
    gm.rows[t] = kRows[t];
    gm.off[t] = kOff[t];
  }
  gather_all<<<dim3(12500, 6), 256, 0, stream>>>(gm, xA);

  dim3 egrid(1172, NREL);
  hist_kernel<<<egrid, 256, 0, stream>>>(rm, counts);
  scan1<<<534, 1024, 0, stream>>>(counts, partials);
  scan2<<<1, 1024, 0, stream>>>(partials, 534);
  scan3<<<534, 1024, 0, stream>>>(counts, prefix, partials);
  scatter_kernel<<<egrid, 256, 0, stream>>>(rm, counts, esrc);

  float* xc = xA;
  float* xn = xB;
  for (int l = 0; l < 4; ++l) {
    int doRelu = (l < 3);
    _Float16* LW = Wt + (size_t)l * PLW;

    // 1) means of x_v for small-dst relations
    AggMeta am;
    for (int t = 0; t < 5; ++t) {
      am.rp[t] = prefix + kCbcIn[t];
      am.mean[t] = meanS + (size_t)kYOff[t] * 128;
      am.M[t] = kRows[kSmallT[t]];
    }
    agg_small<<<dim3(2500, 5), 256, 0, stream>>>(am, xc + (size_t)kOff[1] * 128, esrc);

    // 2) small-dst: [mean | x_dst] @ [Wl;Wr] + b (+relu)   (5 tasks)
    MMeta m1;
    m1.nTasks = 5;
    for (int t = 0; t < 5; ++t) {
      m1.t[t].A0 = meanS + (size_t)kYOff[t] * 128;
      m1.t[t].A1 = xc + (size_t)kOff[kSmallT[t]] * 128;
      m1.t[t].W = LW + (size_t)t * 67584;
      m1.t[t].bias = b_l + (size_t)(l * 10 + kInRel[t]) * 128;
      m1.t[t].out = xn + (size_t)kOff[kSmallT[t]] * 128;
      m1.t[t].M = kRows[kSmallT[t]];
      m1.t[t].blkOff = kBOff[t];
      m1.t[t].K = 256;
      m1.t[t].relu = doRelu;
    }
    mgemm<<<dim3(363), 256, 0, stream>>>(m1);

    // 3) Y_q = x_src @ Wl_q (into meanS, now dead) ; xn_v = x_v @ SumWr + Sumb
    MMeta m2;
    m2.nTasks = 6;
    for (int q = 0; q < 5; ++q) {
      m2.t[q].A0 = xc + (size_t)kOff[kSmallT[q]] * 128;
      m2.t[q].A1 = nullptr;
      m2.t[q].W = LW + 337920 + (size_t)q * 34816;
      m2.t[q].bias = nullptr;
      m2.t[q].out = meanS + (size_t)kYOff[q] * 128;
      m2.t[q].M = kRows[kSmallT[q]];
      m2.t[q].blkOff = kBOff[q];
      m2.t[q].K = 128;
      m2.t[q].relu = 0;
    }
    m2.t[5].A0 = xc + (size_t)kOff[1] * 128;
    m2.t[5].A1 = nullptr;
    m2.t[5].W = LW + 512000;
    m2.t[5].bias = visitSumB + l * 128;
    m2.t[5].out = xn + (size_t)kOff[1] * 128;
    m2.t[5].M = NVISIT;
    m2.t[5].blkOff = 363;
    m2.t[5].K = 128;
    m2.t[5].relu = 0;
    mgemm<<<dim3(363 + 782), 256, 0, stream>>>(m2);

    // 4) xn_v += sum_r mean_r(Y_r); relu
    VAggMeta va;
    for (int q = 0; q < 5; ++q) {
      va.rp[q] = prefix + kCbcVisit[q];
      va.Y[q] = meanS + (size_t)kYOff[q] * 128;
    }
    agg_visit<<<dim3(12500), 256, 0, stream>>>(va, esrc, xn + (size_t)kOff[1] * 128, doRelu);

    float* tmp = xc; xc = xn; xn = tmp;
  }

  const int ML = 200000;
  mgemm_cls<<<dim3((ML + 127) / 128), 256, 0, stream>>>(
      xc + (size_t)kOff[1] * 128, xc + (size_t)kOff[5] * 128, eli,
      Wt + (size_t)4 * PLW, cb1, cw2, cb2, ylab,
      (float*)d_out, (float*)d_out + 1, ML);
}